// Round 14
// baseline (203.837 us; speedup 1.0000x reference)
//
#include <hip/hip_runtime.h>
#include <hip/hip_bf16.h>
#include <stdint.h>

typedef int i32x4 __attribute__((ext_vector_type(4)));

#define AS1 __attribute__((address_space(1)))
#define AS3 __attribute__((address_space(3)))

__constant__ float c_nf4[16] = {
    -1.0f, -0.6961928009986877f, -0.5250730514526367f, -0.39491748809814453f,
    -0.28444138169288635f, -0.18477343022823334f, -0.09105003625154495f, 0.0f,
    0.07958029955625534f, 0.16093020141124725f, 0.24611230194568634f,
    0.33791524171829224f, 0.44070982933044434f, 0.5626170039176941f,
    0.7229568362236023f, 1.0f};

// ---------------------------------------------------------------------------
// Fused row-quantize prep (R13, verified). Block row r in [0,OUT): W_eff row
// -> int8 + sw. Block row in [OUT, OUT+M): X row -> int8 + sx.
// ---------------------------------------------------------------------------
__global__ __launch_bounds__(256) void k_prepq(
    const int* __restrict__ q, const float* __restrict__ scale,
    const float* __restrict__ lA, const float* __restrict__ lB,
    const float* __restrict__ x, int8_t* __restrict__ Wq,
    int8_t* __restrict__ Xq, float* __restrict__ sw, float* __restrict__ sx,
    int IN, int R, int OUT) {
  const int row = blockIdx.x;
  const int t = threadIdx.x;
  const int i0 = t * 16;
  float v[16];

  if (row < OUT) {
    const long e0 = (long)row * IN + i0;
    const float s = scale[e0 >> 6];  // 16 elems lie within one 64-group
    const int* qp = q + e0;
#pragma unroll
    for (int c = 0; c < 4; ++c) {
      int4 qa = *(const int4*)(qp + c * 4);
      v[c * 4 + 0] = c_nf4[qa.x & 15] * s;
      v[c * 4 + 1] = c_nf4[qa.y & 15] * s;
      v[c * 4 + 2] = c_nf4[qa.z & 15] * s;
      v[c * 4 + 3] = c_nf4[qa.w & 15] * s;
    }
    for (int r = 0; r < R; ++r) {
      const float br = 4.0f * lB[row * R + r];
      const float* ap = lA + (long)r * IN + i0;
#pragma unroll
      for (int c = 0; c < 4; ++c) {
        float4 a = *(const float4*)(ap + c * 4);
        v[c * 4 + 0] += br * a.x; v[c * 4 + 1] += br * a.y;
        v[c * 4 + 2] += br * a.z; v[c * 4 + 3] += br * a.w;
      }
    }
  } else {
    const int xr = row - OUT;
    const float* xp = x + (long)xr * IN + i0;
#pragma unroll
    for (int c = 0; c < 4; ++c) {
      float4 a = *(const float4*)(xp + c * 4);
      v[c * 4 + 0] = a.x; v[c * 4 + 1] = a.y;
      v[c * 4 + 2] = a.z; v[c * 4 + 3] = a.w;
    }
  }

  float am = 0.0f;
#pragma unroll
  for (int i = 0; i < 16; ++i) am = fmaxf(am, fabsf(v[i]));
#pragma unroll
  for (int m = 32; m >= 1; m >>= 1) am = fmaxf(am, __shfl_xor(am, m));
  __shared__ float red[4];
  if ((t & 63) == 0) red[t >> 6] = am;
  __syncthreads();
  am = fmaxf(fmaxf(red[0], red[1]), fmaxf(red[2], red[3]));
  am = fmaxf(am, 1e-30f);
  const float inv = 127.0f / am;

  union { int8_t c[16]; int4 p; } pk;
#pragma unroll
  for (int i = 0; i < 16; ++i) pk.c[i] = (int8_t)(int)rintf(v[i] * inv);

  if (row < OUT) {
    *(int4*)(Wq + (long)row * IN + i0) = pk.p;
    if (t == 0) sw[row] = am * (1.0f / 127.0f);
  } else {
    const int xr = row - OUT;
    *(int4*)(Xq + (long)xr * IN + i0) = pk.p;
    if (t == 0) sx[xr] = am * (1.0f / 127.0f);
  }
}

// ---------------------------------------------------------------------------
// 256x256 tile, BK=128 (i8), 8 waves (2M x 4N). R14: TWO phases per K-tile
// (2 x 32-MFMA clusters), 2 barriers + 1 counted VM8 per tile (vs 4 in R13).
//  p0: LGK0; MFMA mq0 x {b0,b1}; rd afB(buf);                       BAR
//  p1: LGK0; MFMA mq1 x {b0,b1}; stage t+2->buf; VM8;               BAR;
//      pre-read afA,b0,b1 of buf^1
// Race discipline: afB reads issued before p0's BAR, region re-staged after
// that BAR + >=300cy memory latency (one-barrier-separation, validated by
// R6/R13's B-staging). Pre-reads follow the all-waves VM8->BAR pair. VM8
// drains t-1's 8 stages = tile t+1's data, 1.5-tile lead >> HBM latency.
// ---------------------------------------------------------------------------
__global__ __launch_bounds__(512, 2) void k_gemm_256(
    const int8_t* __restrict__ Xq, const int8_t* __restrict__ Wq,
    const float* __restrict__ sx, const float* __restrict__ sw,
    const float* __restrict__ bias, float* __restrict__ out,
    int M, int N, int K) {
  __shared__ char smem[131072];
  const int tid = threadIdx.x;
  const int wid = tid >> 6;
  const int lane = tid & 63;
  const int wr = wid >> 2;
  const int wc = wid & 3;
  const int wcl = wc & 1;
  const int l15 = lane & 15;
  const int l16 = lane >> 4;

  // reader swizzle decomposition: (kk*64 + l16*16) ^ ((l15&7)<<4)  [bytes]
  const int kflip = (l15 & 4) ? 64 : 0;
  const int lowx = ((l16 ^ (l15 & 3)) << 4);
  const int baseA0 = wr * 16384 + l15 * 128 + lowx + kflip;
  const int baseA1 = wr * 16384 + l15 * 128 + lowx + (64 ^ kflip);
  const int baseB0 = 65536 + (wc >> 1) * 16384 + wcl * 8192 + l15 * 128 + lowx + kflip;
  const int baseB1 = baseB0 + (64 ^ kflip) - kflip;

  int bid = blockIdx.x;
  const int nwg = gridDim.x;
  if ((nwg & 7) == 0) { const int cpx = nwg >> 3; bid = (bid & 7) * cpx + (bid >> 3); }
  const int nbn = N >> 8;
  const int m0 = (bid / nbn) << 8;
  const int n0 = (bid % nbn) << 8;

  // per-lane pre-swizzled global byte offsets for staging
  int rowj[2], gcj[2];
#pragma unroll
  for (int j = 0; j < 2; ++j) {
    const int lo = wid * 2048 + j * 1024 + lane * 16;
    const int row = lo >> 7;
    const int ls = lo ^ ((row & 7) << 4);
    rowj[j] = row;
    gcj[j] = ls & 127;  // byte col within 128-B K-tile row
  }
  const size_t halfstep = (size_t)128 * K;
  const int8_t* pSA0[2]; const int8_t* pSA1[2];
  const int8_t* pSB0[2]; const int8_t* pSB1[2];
#pragma unroll
  for (int j = 0; j < 2; ++j) {
    pSA0[j] = Xq + (size_t)(m0 + rowj[j]) * K + gcj[j];
    pSA1[j] = pSA0[j] + halfstep;
    pSB0[j] = Wq + (size_t)(n0 + rowj[j]) * K + gcj[j];
    pSB1[j] = pSB0[j] + halfstep;
  }

#define ST_A(bufl, h, coff)                                                          \
  {                                                                                  \
    __builtin_amdgcn_global_load_lds((const AS1 void*)(pSA##h[0] + (coff)),          \
        (AS3 void*)(smem + (bufl) * 32768 + (h) * 16384 + wid * 2048), 16, 0, 0);    \
    __builtin_amdgcn_global_load_lds((const AS1 void*)(pSA##h[1] + (coff)),          \
        (AS3 void*)(smem + (bufl) * 32768 + (h) * 16384 + wid * 2048 + 1024),        \
        16, 0, 0);                                                                   \
  }
#define ST_B(bufl, h, coff)                                                          \
  {                                                                                  \
    __builtin_amdgcn_global_load_lds((const AS1 void*)(pSB##h[0] + (coff)),          \
        (AS3 void*)(smem + 65536 + (bufl) * 32768 + (h) * 16384 + wid * 2048),       \
        16, 0, 0);                                                                   \
    __builtin_amdgcn_global_load_lds((const AS1 void*)(pSB##h[1] + (coff)),          \
        (AS3 void*)(smem + 65536 + (bufl) * 32768 + (h) * 16384 + wid * 2048 + 1024),\
        16, 0, 0);                                                                   \
  }

  i32x4 afA[4][2], afB[4][2], b0[2][2], b1[2][2];
  i32x4 acc[8][4];
#pragma unroll
  for (int i = 0; i < 8; ++i)
#pragma unroll
    for (int j = 0; j < 4; ++j) acc[i][j] = (i32x4)0;

#define RD_A(bufl, mq, dst)                                                          \
  _Pragma("unroll") for (int ii = 0; ii < 4; ++ii) {                                 \
    dst[ii][0] = *(const i32x4*)(smem + baseA0 +                                     \
                                 ((bufl) * 32768 + (mq) * 8192 + ii * 2048));        \
    dst[ii][1] = *(const i32x4*)(smem + baseA1 +                                     \
                                 ((bufl) * 32768 + (mq) * 8192 + ii * 2048));        \
  }
#define RD_B(bufl, q, arr)                                                           \
  _Pragma("unroll") for (int jj = 0; jj < 2; ++jj) {                                 \
    arr[jj][0] = *(const i32x4*)(smem + baseB0 +                                     \
                                 ((bufl) * 32768 + (q) * 4096 + jj * 2048));         \
    arr[jj][1] = *(const i32x4*)(smem + baseB1 +                                     \
                                 ((bufl) * 32768 + (q) * 4096 + jj * 2048));         \
  }
#define MFMA_Q(mq, q, A, arr)                                                        \
  _Pragma("unroll") for (int kk = 0; kk < 2; ++kk)                                   \
  _Pragma("unroll") for (int ii = 0; ii < 4; ++ii)                                   \
  _Pragma("unroll") for (int jj = 0; jj < 2; ++jj)                                   \
      acc[(mq)*4+ii][(q)*2+jj] = __builtin_amdgcn_mfma_i32_16x16x64_i8(              \
          A[ii][kk], arr[jj][kk], acc[(mq)*4+ii][(q)*2+jj], 0, 0, 0);

#define BAR __builtin_amdgcn_s_barrier()
#define PRIO1 __builtin_amdgcn_s_setprio(1)
#define PRIO0 __builtin_amdgcn_s_setprio(0)
#define LGK0                                               \
  {                                                        \
    asm volatile("s_waitcnt lgkmcnt(0)" ::: "memory");     \
    __builtin_amdgcn_sched_barrier(0);                     \
  }
#define VM8 asm volatile("s_waitcnt vmcnt(8)" ::: "memory")

  // Two-phase subtile: [wait; 32-MFMA cluster; next ops; BAR] x 2
#define SUBTILE(bufl, SC)                                                            \
  /* p0: mq0 x {b0,b1}; read afB of bufl */                                          \
  LGK0; PRIO1; MFMA_Q(0, 0, afA, b0) MFMA_Q(0, 1, afA, b1) PRIO0;                    \
  RD_A(bufl, 1, afB)                                                                 \
  BAR;                                                                               \
  /* p1: mq1 x {b0,b1}; stage t+2 -> bufl; drain t-1 stages; pre-read buf^1 */       \
  LGK0; PRIO1; MFMA_Q(1, 0, afB, b0) MFMA_Q(1, 1, afB, b1) PRIO0;                    \
  ST_B(bufl, 0, SC) ST_B(bufl, 1, SC)                                                \
  ST_A(bufl, 0, SC) ST_A(bufl, 1, SC)                                                \
  VM8;                                                                               \
  BAR;                                                                               \
  RD_A((bufl) ^ 1, 0, afA)                                                           \
  RD_B((bufl) ^ 1, 0, b0)                                                            \
  RD_B((bufl) ^ 1, 1, b1)

  const int NT = K >> 7;   // BK = 128 i8

  // prologue: stage tile0->buf0, tile1->buf1; drain tile0; pre-read afA,b0,b1
  ST_A(0, 0, 0) ST_A(0, 1, 0) ST_B(0, 0, 0) ST_B(0, 1, 0)
  ST_A(1, 0, 128) ST_A(1, 1, 128) ST_B(1, 0, 128) ST_B(1, 1, 128)
  VM8;
  BAR;
  RD_A(0, 0, afA)
  RD_B(0, 0, b0)
  RD_B(0, 1, b1)
#pragma unroll
  for (int j = 0; j < 2; ++j) { pSA0[j] += 256; pSA1[j] += 256; pSB0[j] += 256; pSB1[j] += 256; }

  for (int t = 0; t < NT; t += 2) {
    SUBTILE(0, 0)
    SUBTILE(1, 128)
    if (t + 4 < NT) {
#pragma unroll
      for (int j = 0; j < 2; ++j) { pSA0[j] += 256; pSA1[j] += 256; pSB0[j] += 256; pSB1[j] += 256; }
    }
  }

  // epilogue: C/D col=lane&15, row=(lane>>4)*4+j; out = sx*sw*acc + bias
  float bv[4], swc[4];
#pragma unroll
  for (int nf = 0; nf < 4; ++nf) {
    const int col = n0 + wc * 64 + nf * 16 + l15;
    bv[nf] = bias[col];
    swc[nf] = sw[col];
  }
#pragma unroll
  for (int mi = 0; mi < 8; ++mi) {
    const int rbase = m0 + wr * 128 + mi * 16 + l16 * 4;
    const float4 sx4 = *(const float4*)(sx + rbase);
#pragma unroll
    for (int nf = 0; nf < 4; ++nf) {
      const int col = n0 + wc * 64 + nf * 16 + l15;
      const float s0 = sx4.x * swc[nf], s1 = sx4.y * swc[nf];
      const float s2 = sx4.z * swc[nf], s3 = sx4.w * swc[nf];
      out[(size_t)(rbase + 0) * N + col] = (float)acc[mi][nf][0] * s0 + bv[nf];
      out[(size_t)(rbase + 1) * N + col] = (float)acc[mi][nf][1] * s1 + bv[nf];
      out[(size_t)(rbase + 2) * N + col] = (float)acc[mi][nf][2] * s2 + bv[nf];
      out[(size_t)(rbase + 3) * N + col] = (float)acc[mi][nf][3] * s3 + bv[nf];
    }
  }
#undef ST_A
#undef ST_B
#undef RD_A
#undef RD_B
#undef MFMA_Q
#undef BAR
#undef PRIO1
#undef PRIO0
#undef LGK0
#undef VM8
#undef SUBTILE
}

extern "C" void kernel_launch(void* const* d_in, const int* in_sizes, int n_in,
                              void* d_out, int out_size, void* d_ws, size_t ws_size,
                              hipStream_t stream) {
  const float* x = (const float*)d_in[0];
  const int* qw = (const int*)d_in[1];
  const float* qs = (const float*)d_in[2];
  const float* bias = (const float*)d_in[3];
  const float* lA = (const float*)d_in[4];
  const float* lB = (const float*)d_in[5];
  float* out = (float*)d_out;

  const int OUT = in_sizes[3];
  const long qn = (long)in_sizes[1];
  const int IN = (int)(qn / OUT);
  const int R = in_sizes[5] / OUT;
  const long xn = (long)in_sizes[0];
  const int M = (int)(xn / IN);
  const int N = OUT, K = IN;

  // workspace: Wq[qn] i8 | Xq[xn] i8 | sw[OUT] f32 | sx[M] f32 (16B aligned)
  int8_t* Wq = (int8_t*)d_ws;
  int8_t* Xq = Wq + qn;
  float* sw = (float*)(((uintptr_t)(Xq + xn) + 15) & ~(uintptr_t)15);
  float* sx = sw + OUT;

  k_prepq<<<OUT + M, 256, 0, stream>>>(qw, qs, lA, lB, x, Wq, Xq, sw, sx, IN, R, OUT);

  dim3 grid((M / 256) * (N / 256));
  k_gemm_256<<<grid, 512, 0, stream>>>(Xq, Wq, sx, sw, bias, out, M, N, K);
}

// Round 15
// 200.261 us; speedup vs baseline: 1.0179x; 1.0179x over previous
//
#include <hip/hip_runtime.h>
#include <hip/hip_bf16.h>
#include <stdint.h>

typedef int i32x4 __attribute__((ext_vector_type(4)));

#define AS1 __attribute__((address_space(1)))
#define AS3 __attribute__((address_space(3)))

__constant__ float c_nf4[16] = {
    -1.0f, -0.6961928009986877f, -0.5250730514526367f, -0.39491748809814453f,
    -0.28444138169288635f, -0.18477343022823334f, -0.09105003625154495f, 0.0f,
    0.07958029955625534f, 0.16093020141124725f, 0.24611230194568634f,
    0.33791524171829224f, 0.44070982933044434f, 0.5626170039176941f,
    0.7229568362236023f, 1.0f};

// ---------------------------------------------------------------------------
// R15 prep: ONE ROW PER WAVE (4 rows/block). Lane owns 64 elems (4 chunks of
// 16, kept in registers); row absmax = local max + 6x shfl_xor (no LDS, no
// barrier); quantize from regs. Rows [0,OUT) = W_eff (dequant+LoRA fold);
// rows [OUT,OUT+M) = X. Exact same math as R13 -> bit-identical output.
// ---------------------------------------------------------------------------
__global__ __launch_bounds__(256) void k_prepq(
    const int* __restrict__ q, const float* __restrict__ scale,
    const float* __restrict__ lA, const float* __restrict__ lB,
    const float* __restrict__ x, int8_t* __restrict__ Wq,
    int8_t* __restrict__ Xq, float* __restrict__ sw, float* __restrict__ sx,
    int IN, int R, int OUT, int nrows) {
  const int lane = threadIdx.x & 63;
  const int row = blockIdx.x * 4 + (threadIdx.x >> 6);
  if (row >= nrows) return;

  float v[64];

  if (row < OUT) {
    const long rbase = (long)row * IN;
    float br[8];
#pragma unroll
    for (int r = 0; r < 8; ++r) br[r] = (r < R) ? 4.0f * lB[row * R + r] : 0.0f;
#pragma unroll
    for (int c = 0; c < 4; ++c) {
      const int e0 = c * 1024 + lane * 16;
      const float s = scale[(rbase + e0) >> 6];  // 16 elems within one 64-group
      const int* qp = q + rbase + e0;
#pragma unroll
      for (int u = 0; u < 4; ++u) {
        int4 qa = *(const int4*)(qp + u * 4);
        v[c * 16 + u * 4 + 0] = c_nf4[qa.x & 15] * s;
        v[c * 16 + u * 4 + 1] = c_nf4[qa.y & 15] * s;
        v[c * 16 + u * 4 + 2] = c_nf4[qa.z & 15] * s;
        v[c * 16 + u * 4 + 3] = c_nf4[qa.w & 15] * s;
      }
      for (int r = 0; r < R; ++r) {
        const float* ap = lA + (long)r * IN + e0;
#pragma unroll
        for (int u = 0; u < 4; ++u) {
          float4 a = *(const float4*)(ap + u * 4);
          v[c * 16 + u * 4 + 0] += br[r] * a.x;
          v[c * 16 + u * 4 + 1] += br[r] * a.y;
          v[c * 16 + u * 4 + 2] += br[r] * a.z;
          v[c * 16 + u * 4 + 3] += br[r] * a.w;
        }
      }
    }
  } else {
    const float* xp = x + (long)(row - OUT) * IN;
#pragma unroll
    for (int c = 0; c < 4; ++c) {
      const int e0 = c * 1024 + lane * 16;
#pragma unroll
      for (int u = 0; u < 4; ++u) {
        float4 a = *(const float4*)(xp + e0 + u * 4);
        v[c * 16 + u * 4 + 0] = a.x; v[c * 16 + u * 4 + 1] = a.y;
        v[c * 16 + u * 4 + 2] = a.z; v[c * 16 + u * 4 + 3] = a.w;
      }
    }
  }

  float am = 0.0f;
#pragma unroll
  for (int i = 0; i < 64; ++i) am = fmaxf(am, fabsf(v[i]));
#pragma unroll
  for (int m = 32; m >= 1; m >>= 1) am = fmaxf(am, __shfl_xor(am, m));
  am = fmaxf(am, 1e-30f);
  const float inv = 127.0f / am;

  int8_t* dst = (row < OUT) ? (Wq + (long)row * IN) : (Xq + (long)(row - OUT) * IN);
#pragma unroll
  for (int c = 0; c < 4; ++c) {
    union { int8_t b[16]; int4 p; } pk;
#pragma unroll
    for (int i = 0; i < 16; ++i)
      pk.b[i] = (int8_t)(int)rintf(v[c * 16 + i] * inv);
    *(int4*)(dst + c * 1024 + lane * 16) = pk.p;
  }
  if (lane == 0) {
    if (row < OUT) sw[row] = am * (1.0f / 127.0f);
    else sx[row - OUT] = am * (1.0f / 127.0f);
  }
}

// ---------------------------------------------------------------------------
// CHAMPION GEMM (R13, verified 126us / 47.6% MfmaUtil / 0 conflicts):
// 256x256 tile, BK=128 (i8), 8 waves (2M x 4N), 4 phases/tile, reads-early
// R6 schedule, mfma_i32_16x16x64_i8, exact int32 accumulation.
// Epilogue: out = sx[row]*sw[col]*acc + bias[col].
// ---------------------------------------------------------------------------
__global__ __launch_bounds__(512, 2) void k_gemm_256(
    const int8_t* __restrict__ Xq, const int8_t* __restrict__ Wq,
    const float* __restrict__ sx, const float* __restrict__ sw,
    const float* __restrict__ bias, float* __restrict__ out,
    int M, int N, int K) {
  __shared__ char smem[131072];
  const int tid = threadIdx.x;
  const int wid = tid >> 6;
  const int lane = tid & 63;
  const int wr = wid >> 2;
  const int wc = wid & 3;
  const int wcl = wc & 1;
  const int l15 = lane & 15;
  const int l16 = lane >> 4;

  const int kflip = (l15 & 4) ? 64 : 0;
  const int lowx = ((l16 ^ (l15 & 3)) << 4);
  const int baseA0 = wr * 16384 + l15 * 128 + lowx + kflip;
  const int baseA1 = wr * 16384 + l15 * 128 + lowx + (64 ^ kflip);
  const int baseB0 = 65536 + (wc >> 1) * 16384 + wcl * 8192 + l15 * 128 + lowx + kflip;
  const int baseB1 = baseB0 + (64 ^ kflip) - kflip;

  int bid = blockIdx.x;
  const int nwg = gridDim.x;
  if ((nwg & 7) == 0) { const int cpx = nwg >> 3; bid = (bid & 7) * cpx + (bid >> 3); }
  const int nbn = N >> 8;
  const int m0 = (bid / nbn) << 8;
  const int n0 = (bid % nbn) << 8;

  int rowj[2], gcj[2];
#pragma unroll
  for (int j = 0; j < 2; ++j) {
    const int lo = wid * 2048 + j * 1024 + lane * 16;
    const int row = lo >> 7;
    const int ls = lo ^ ((row & 7) << 4);
    rowj[j] = row;
    gcj[j] = ls & 127;
  }
  const size_t halfstep = (size_t)128 * K;
  const int8_t* pSA0[2]; const int8_t* pSA1[2];
  const int8_t* pSB0[2]; const int8_t* pSB1[2];
#pragma unroll
  for (int j = 0; j < 2; ++j) {
    pSA0[j] = Xq + (size_t)(m0 + rowj[j]) * K + gcj[j];
    pSA1[j] = pSA0[j] + halfstep;
    pSB0[j] = Wq + (size_t)(n0 + rowj[j]) * K + gcj[j];
    pSB1[j] = pSB0[j] + halfstep;
  }

#define ST_A(bufl, h, coff)                                                          \
  {                                                                                  \
    __builtin_amdgcn_global_load_lds((const AS1 void*)(pSA##h[0] + (coff)),          \
        (AS3 void*)(smem + (bufl) * 32768 + (h) * 16384 + wid * 2048), 16, 0, 0);    \
    __builtin_amdgcn_global_load_lds((const AS1 void*)(pSA##h[1] + (coff)),          \
        (AS3 void*)(smem + (bufl) * 32768 + (h) * 16384 + wid * 2048 + 1024),        \
        16, 0, 0);                                                                   \
  }
#define ST_B(bufl, h, coff)                                                          \
  {                                                                                  \
    __builtin_amdgcn_global_load_lds((const AS1 void*)(pSB##h[0] + (coff)),          \
        (AS3 void*)(smem + 65536 + (bufl) * 32768 + (h) * 16384 + wid * 2048),       \
        16, 0, 0);                                                                   \
    __builtin_amdgcn_global_load_lds((const AS1 void*)(pSB##h[1] + (coff)),          \
        (AS3 void*)(smem + 65536 + (bufl) * 32768 + (h) * 16384 + wid * 2048 + 1024),\
        16, 0, 0);                                                                   \
  }

  i32x4 afA[4][2], afB[4][2], b0[2][2], b1[2][2];
  i32x4 acc[8][4];
#pragma unroll
  for (int i = 0; i < 8; ++i)
#pragma unroll
    for (int j = 0; j < 4; ++j) acc[i][j] = (i32x4)0;

#define RD_A(bufl, mq, dst)                                                          \
  _Pragma("unroll") for (int ii = 0; ii < 4; ++ii) {                                 \
    dst[ii][0] = *(const i32x4*)(smem + baseA0 +                                     \
                                 ((bufl) * 32768 + (mq) * 8192 + ii * 2048));        \
    dst[ii][1] = *(const i32x4*)(smem + baseA1 +                                     \
                                 ((bufl) * 32768 + (mq) * 8192 + ii * 2048));        \
  }
#define RD_B(bufl, q, arr)                                                           \
  _Pragma("unroll") for (int jj = 0; jj < 2; ++jj) {                                 \
    arr[jj][0] = *(const i32x4*)(smem + baseB0 +                                     \
                                 ((bufl) * 32768 + (q) * 4096 + jj * 2048));         \
    arr[jj][1] = *(const i32x4*)(smem + baseB1 +                                     \
                                 ((bufl) * 32768 + (q) * 4096 + jj * 2048));         \
  }
#define MFMA_Q(mq, q, A, arr)                                                        \
  _Pragma("unroll") for (int kk = 0; kk < 2; ++kk)                                   \
  _Pragma("unroll") for (int ii = 0; ii < 4; ++ii)                                   \
  _Pragma("unroll") for (int jj = 0; jj < 2; ++jj)                                   \
      acc[(mq)*4+ii][(q)*2+jj] = __builtin_amdgcn_mfma_i32_16x16x64_i8(              \
          A[ii][kk], arr[jj][kk], acc[(mq)*4+ii][(q)*2+jj], 0, 0, 0);

#define BAR __builtin_amdgcn_s_barrier()
#define PRIO1 __builtin_amdgcn_s_setprio(1)
#define PRIO0 __builtin_amdgcn_s_setprio(0)
#define LGK0                                               \
  {                                                        \
    asm volatile("s_waitcnt lgkmcnt(0)" ::: "memory");     \
    __builtin_amdgcn_sched_barrier(0);                     \
  }
#define VM4 asm volatile("s_waitcnt vmcnt(4)" ::: "memory")
#define VM8 asm volatile("s_waitcnt vmcnt(8)" ::: "memory")

#define SUBTILE(bufl, SC)                                                            \
  /* p0 */                                                                           \
  LGK0; PRIO1; MFMA_Q(0, 0, afA, b0) PRIO0;                                          \
  RD_B(bufl, 1, b1)                                                                  \
  BAR;                                                                               \
  /* p1 */                                                                           \
  LGK0; PRIO1; MFMA_Q(0, 1, afA, b1) PRIO0;                                          \
  RD_A(bufl, 1, afB)                                                                 \
  BAR;                                                                               \
  /* p2: B of bufl fully consumed -> stage B(t+2) */                                 \
  LGK0; PRIO1; MFMA_Q(1, 0, afB, b0) PRIO0;                                          \
  ST_B(bufl, 0, SC) ST_B(bufl, 1, SC)                                                \
  VM4;                                                                               \
  BAR;                                                                               \
  /* p3: A of bufl consumed -> stage A(t+2); pre-read next tile's afA,b0 */          \
  PRIO1; MFMA_Q(1, 1, afB, b1) PRIO0;                                                \
  ST_A(bufl, 0, SC) ST_A(bufl, 1, SC)                                                \
  RD_A((bufl) ^ 1, 0, afA)                                                           \
  RD_B((bufl) ^ 1, 0, b0)                                                            \
  BAR;

  const int NT = K >> 7;   // BK = 128 i8

  ST_A(0, 0, 0) ST_A(0, 1, 0) ST_B(0, 0, 0) ST_B(0, 1, 0)
  ST_A(1, 0, 128) ST_A(1, 1, 128) ST_B(1, 0, 128) ST_B(1, 1, 128)
  VM8;
  BAR;
  RD_A(0, 0, afA)
  RD_B(0, 0, b0)
#pragma unroll
  for (int j = 0; j < 2; ++j) { pSA0[j] += 256; pSA1[j] += 256; pSB0[j] += 256; pSB1[j] += 256; }

  for (int t = 0; t < NT; t += 2) {
    SUBTILE(0, 0)
    SUBTILE(1, 128)
    if (t + 4 < NT) {
#pragma unroll
      for (int j = 0; j < 2; ++j) { pSA0[j] += 256; pSA1[j] += 256; pSB0[j] += 256; pSB1[j] += 256; }
    }
  }

  // epilogue: C/D col=lane&15, row=(lane>>4)*4+j; out = sx*sw*acc + bias
  float bv[4], swc[4];
#pragma unroll
  for (int nf = 0; nf < 4; ++nf) {
    const int col = n0 + wc * 64 + nf * 16 + l15;
    bv[nf] = bias[col];
    swc[nf] = sw[col];
  }
#pragma unroll
  for (int mi = 0; mi < 8; ++mi) {
    const int rbase = m0 + wr * 128 + mi * 16 + l16 * 4;
    const float4 sx4 = *(const float4*)(sx + rbase);
#pragma unroll
    for (int nf = 0; nf < 4; ++nf) {
      const int col = n0 + wc * 64 + nf * 16 + l15;
      const float s0 = sx4.x * swc[nf], s1 = sx4.y * swc[nf];
      const float s2 = sx4.z * swc[nf], s3 = sx4.w * swc[nf];
      out[(size_t)(rbase + 0) * N + col] = (float)acc[mi][nf][0] * s0 + bv[nf];
      out[(size_t)(rbase + 1) * N + col] = (float)acc[mi][nf][1] * s1 + bv[nf];
      out[(size_t)(rbase + 2) * N + col] = (float)acc[mi][nf][2] * s2 + bv[nf];
      out[(size_t)(rbase + 3) * N + col] = (float)acc[mi][nf][3] * s3 + bv[nf];
    }
  }
#undef ST_A
#undef ST_B
#undef RD_A
#undef RD_B
#undef MFMA_Q
#undef BAR
#undef PRIO1
#undef PRIO0
#undef LGK0
#undef VM4
#undef VM8
#undef SUBTILE
}

extern "C" void kernel_launch(void* const* d_in, const int* in_sizes, int n_in,
                              void* d_out, int out_size, void* d_ws, size_t ws_size,
                              hipStream_t stream) {
  const float* x = (const float*)d_in[0];
  const int* qw = (const int*)d_in[1];
  const float* qs = (const float*)d_in[2];
  const float* bias = (const float*)d_in[3];
  const float* lA = (const float*)d_in[4];
  const float* lB = (const float*)d_in[5];
  float* out = (float*)d_out;

  const int OUT = in_sizes[3];
  const long qn = (long)in_sizes[1];
  const int IN = (int)(qn / OUT);
  const int R = in_sizes[5] / OUT;
  const long xn = (long)in_sizes[0];
  const int M = (int)(xn / IN);
  const int N = OUT, K = IN;

  // workspace: Wq[qn] i8 | Xq[xn] i8 | sw[OUT] f32 | sx[M] f32 (16B aligned)
  int8_t* Wq = (int8_t*)d_ws;
  int8_t* Xq = Wq + qn;
  float* sw = (float*)(((uintptr_t)(Xq + xn) + 15) & ~(uintptr_t)15);
  float* sx = sw + OUT;

  const int nrows = OUT + M;
  k_prepq<<<(nrows + 3) / 4, 256, 0, stream>>>(qw, qs, lA, lB, x, Wq, Xq, sw, sx,
                                               IN, R, OUT, nrows);

  dim3 grid((M / 256) * (N / 256));
  k_gemm_256<<<grid, 512, 0, stream>>>(Xq, Wq, sx, sw, bias, out, M, N, K);
}